// Round 1
// baseline (4877.633 us; speedup 1.0000x reference)
//
#include <hip/hip_runtime.h>
#include <hip/hip_bf16.h>
#include <math.h>

// Problem dims (fixed by reference)
#define T_STEPS 512
#define BATCH   64
#define DIN     256
#define HID     1024
#define DOUT    256
#define NBLK    64      // persistent blocks in recurrence (<= 256 CUs -> all co-resident)

typedef __attribute__((ext_vector_type(8))) short    bf16x8;
typedef __attribute__((ext_vector_type(4))) float    f32x4;

static __device__ __forceinline__ unsigned short f2bf(float f) {
    union { float f; unsigned u; } v; v.f = f;
    unsigned u = v.u;
    u += 0x7fff + ((u >> 16) & 1);   // round-to-nearest-even
    return (unsigned short)(u >> 16);
}
static __device__ __forceinline__ float bf2f(unsigned short h) {
    union { unsigned u; float f; } v; v.u = ((unsigned)h) << 16; return v.f;
}

// ---------------- convert kernels ----------------
__global__ __launch_bounds__(256) void convert_x(const float* __restrict__ x,
                                                 unsigned short* __restrict__ xb) {
    // 512*64*256 = 8388608 elements, 4 per thread
    size_t i = ((size_t)blockIdx.x * 256 + threadIdx.x) * 4;
    float4 v = *(const float4*)(x + i);
    ushort4 o;
    o.x = f2bf(v.x); o.y = f2bf(v.y); o.z = f2bf(v.z); o.w = f2bf(v.w);
    *(ushort4*)(xb + i) = o;
}

__global__ __launch_bounds__(256) void convert_wxt(const float* __restrict__ Wx,
                                                   unsigned short* __restrict__ wxtb) {
    // Wx[DIN][HID] fp32 -> WxT[HID][DIN] bf16 (coalesced write)
    int o = blockIdx.x * 256 + threadIdx.x;  // 262144 total
    int d = o & (DIN - 1);
    int j = o >> 8;
    wxtb[(size_t)j * DIN + d] = f2bf(Wx[(size_t)d * HID + j]);
}

// ---------------- pre = x @ Wx + b  (M=32768, K=256, N=1024), bf16 out ----------------
__global__ __launch_bounds__(256) void gemm_pre(const unsigned short* __restrict__ xb,
                                                const unsigned short* __restrict__ wxtb,
                                                const float* __restrict__ bias,
                                                unsigned short* __restrict__ pre) {
    int mb = blockIdx.x * 64;
    int nb = blockIdx.y * 64;
    int wave = threadIdx.x >> 6, lane = threadIdx.x & 63;
    int l15 = lane & 15, lkq = lane >> 4;

    f32x4 acc[4] = {};
    const unsigned short* aptr = xb + (size_t)(mb + wave * 16 + l15) * DIN + lkq * 8;
#pragma unroll
    for (int ks = 0; ks < DIN / 32; ++ks) {
        bf16x8 a = *(const bf16x8*)(aptr + ks * 32);
#pragma unroll
        for (int nt = 0; nt < 4; ++nt) {
            const unsigned short* bp =
                wxtb + (size_t)(nb + nt * 16 + l15) * DIN + ks * 32 + lkq * 8;
            bf16x8 b = *(const bf16x8*)bp;
            acc[nt] = __builtin_amdgcn_mfma_f32_16x16x32_bf16(a, b, acc[nt], 0, 0, 0);
        }
    }
#pragma unroll
    for (int nt = 0; nt < 4; ++nt) {
        int col = nb + nt * 16 + l15;
        float bb = bias[col];
#pragma unroll
        for (int r = 0; r < 4; ++r) {
            int row = mb + wave * 16 + lkq * 4 + r;
            pre[(size_t)row * HID + col] = f2bf(acc[nt][r] + bb);
        }
    }
}

// ---------------- persistent recurrence kernel ----------------
// grid = 64 blocks x 256 threads. Block k owns columns [16k,16k+16).
// Wh slice lives in LDS, pre-swizzled into MFMA B-fragment order.
// h double-buffered in global (bf16); one device-scope barrier per step.
__global__ __launch_bounds__(256, 1) void rnn_persistent(const float* __restrict__ Wh,
                                                         const unsigned short* __restrict__ pre,
                                                         unsigned short* __restrict__ hbuf,
                                                         unsigned* __restrict__ cnt) {
    __shared__ unsigned short ldsB[32 * 64 * 8];  // 32 KB, [ks][lane][8 contiguous bf16]
    const int cb = blockIdx.x * 16;
    const int tid = threadIdx.x;

    // Stage + swizzle Wh[:, cb:cb+16] into B-frag layout (one time).
    for (int p = tid; p < 32 * 64; p += 256) {
        int ks = p >> 6, L = p & 63;
        int k0 = ks * 32 + ((L >> 4) * 8);
        int col = cb + (L & 15);
#pragma unroll
        for (int j = 0; j < 8; ++j)
            ldsB[p * 8 + j] = f2bf(Wh[(size_t)(k0 + j) * HID + col]);
    }
    __syncthreads();

    const int wave = tid >> 6, lane = tid & 63;
    const int l15 = lane & 15, lkq = lane >> 4;
    const int row0 = wave * 16;

    // t = 0: h1 = tanh(pre[0]) (h0 == 0), stored in buf[1]
    unsigned short* buf1 = hbuf + (size_t)BATCH * HID;
#pragma unroll
    for (int r = 0; r < 4; ++r) {
        int row = row0 + lkq * 4 + r;
        int col = cb + l15;
        buf1[(size_t)row * HID + col] = f2bf(tanhf(bf2f(pre[(size_t)row * HID + col])));
    }

    // barrier #1
    __syncthreads();
    if (tid == 0) {
        __hip_atomic_fetch_add(cnt, 1u, __ATOMIC_RELEASE, __HIP_MEMORY_SCOPE_AGENT);
        while (__hip_atomic_load(cnt, __ATOMIC_ACQUIRE, __HIP_MEMORY_SCOPE_AGENT) < (unsigned)NBLK)
            __builtin_amdgcn_s_sleep(1);
    }
    __syncthreads();

    for (int t = 1; t <= 510; ++t) {
        const unsigned short* hc = hbuf + (size_t)(t & 1) * BATCH * HID;
        unsigned short* hn = hbuf + (size_t)((t + 1) & 1) * BATCH * HID;

        f32x4 acc0 = {}, acc1 = {};
        const unsigned short* ap = hc + (size_t)(row0 + l15) * HID + lkq * 8;
#pragma unroll
        for (int ks = 0; ks < 32; ks += 2) {
            bf16x8 a0 = *(const bf16x8*)(ap + ks * 32);
            bf16x8 b0 = *(const bf16x8*)&ldsB[((ks)*64 + lane) * 8];
            acc0 = __builtin_amdgcn_mfma_f32_16x16x32_bf16(a0, b0, acc0, 0, 0, 0);
            bf16x8 a1 = *(const bf16x8*)(ap + ks * 32 + 32);
            bf16x8 b1 = *(const bf16x8*)&ldsB[((ks + 1) * 64 + lane) * 8];
            acc1 = __builtin_amdgcn_mfma_f32_16x16x32_bf16(a1, b1, acc1, 0, 0, 0);
        }
        f32x4 acc = acc0 + acc1;

        const unsigned short* pt = pre + (size_t)t * BATCH * HID;
#pragma unroll
        for (int r = 0; r < 4; ++r) {
            int row = row0 + lkq * 4 + r;
            int col = cb + l15;
            float v = acc[r] + bf2f(pt[(size_t)row * HID + col]);
            hn[(size_t)row * HID + col] = f2bf(tanhf(v));
        }

        if (t < 510) {
            __syncthreads();
            if (tid == 0) {
                __hip_atomic_fetch_add(cnt, 1u, __ATOMIC_RELEASE, __HIP_MEMORY_SCOPE_AGENT);
                unsigned goal = (unsigned)(t + 1) * (unsigned)NBLK;
                while (__hip_atomic_load(cnt, __ATOMIC_ACQUIRE, __HIP_MEMORY_SCOPE_AGENT) < goal)
                    __builtin_amdgcn_s_sleep(1);
            }
            __syncthreads();
        }
    }
    // final h (h_511 == H[-2]) sits in buf[1]; next kernel (same stream) consumes it.
}

// ---------------- y = h_final @ W2 + b2 ----------------
__global__ __launch_bounds__(256) void out_gemm(const unsigned short* __restrict__ hfin,
                                                const float* __restrict__ W2,
                                                const float* __restrict__ b2,
                                                float* __restrict__ out) {
    int b = blockIdx.x;        // 64
    int j = threadIdx.x;       // 256
    float acc = b2[j];
    const unsigned short* hr = hfin + (size_t)b * HID;
    for (int k = 0; k < HID; ++k)
        acc = fmaf(bf2f(hr[k]), W2[(size_t)k * DOUT + j], acc);
    out[(size_t)b * DOUT + j] = acc;
}

extern "C" void kernel_launch(void* const* d_in, const int* in_sizes, int n_in,
                              void* d_out, int out_size, void* d_ws, size_t ws_size,
                              hipStream_t stream) {
    const float* x  = (const float*)d_in[0];
    const float* Wx = (const float*)d_in[1];
    const float* Wh = (const float*)d_in[2];
    const float* b  = (const float*)d_in[3];
    const float* W2 = (const float*)d_in[4];
    const float* b2 = (const float*)d_in[5];
    float* out = (float*)d_out;

    // workspace carve (needs ~81 MB)
    char* ws = (char*)d_ws;
    unsigned*       cnt  = (unsigned*)ws;                                  // 256 B
    unsigned short* hbuf = (unsigned short*)(ws + 256);                    // 2*64*1024*2 = 256 KB
    unsigned short* xb   = (unsigned short*)(ws + 256 + 2 * BATCH * HID * 2); // 16 MB
    unsigned short* wxtb = xb + (size_t)T_STEPS * BATCH * DIN;             // 0.5 MB
    unsigned short* pre  = wxtb + (size_t)HID * DIN;                       // 64 MB

    hipMemsetAsync(cnt, 0, 256, stream);
    convert_x<<<8192, 256, 0, stream>>>(x, xb);
    convert_wxt<<<1024, 256, 0, stream>>>(Wx, wxtb);
    gemm_pre<<<dim3(512, 16), 256, 0, stream>>>(xb, wxtb, b, pre);
    rnn_persistent<<<NBLK, 256, 0, stream>>>(Wh, pre, hbuf, cnt);
    out_gemm<<<64, 256, 0, stream>>>(hbuf + (size_t)BATCH * HID, W2, b2, out);
}

// Round 3
// 4762.632 us; speedup vs baseline: 1.0241x; 1.0241x over previous
//
#include <hip/hip_runtime.h>
#include <hip/hip_bf16.h>
#include <math.h>

// Problem dims (fixed by reference)
#define T_STEPS 512
#define BATCH   64
#define DIN     256
#define HID     1024
#define DOUT    256
#define NBLK    64      // persistent blocks in recurrence (<= 256 CUs -> all co-resident)
#define FLAG_STRIDE 16  // flags padded to 64B lines

typedef __attribute__((ext_vector_type(8))) short    bf16x8;
typedef __attribute__((ext_vector_type(4))) float    f32x4;

static __device__ __forceinline__ unsigned short f2bf(float f) {
    union { float f; unsigned u; } v; v.f = f;
    unsigned u = v.u;
    u += 0x7fff + ((u >> 16) & 1);   // round-to-nearest-even
    return (unsigned short)(u >> 16);
}
static __device__ __forceinline__ float bf2f(unsigned short h) {
    union { unsigned u; float f; } v; v.u = ((unsigned)h) << 16; return v.f;
}

// ---------------- convert kernels ----------------
__global__ __launch_bounds__(256) void convert_x(const float* __restrict__ x,
                                                 unsigned short* __restrict__ xb) {
    size_t i = ((size_t)blockIdx.x * 256 + threadIdx.x) * 4;
    float4 v = *(const float4*)(x + i);
    ushort4 o;
    o.x = f2bf(v.x); o.y = f2bf(v.y); o.z = f2bf(v.z); o.w = f2bf(v.w);
    *(ushort4*)(xb + i) = o;
}

__global__ __launch_bounds__(256) void convert_wxt(const float* __restrict__ Wx,
                                                   unsigned short* __restrict__ wxtb) {
    // Wx[DIN][HID] fp32 -> WxT[HID][DIN] bf16 (coalesced write)
    int o = blockIdx.x * 256 + threadIdx.x;  // 262144 total
    int d = o & (DIN - 1);
    int j = o >> 8;
    wxtb[(size_t)j * DIN + d] = f2bf(Wx[(size_t)d * HID + j]);
}

// ---------------- pre = x @ Wx + b  (M=32768, K=256, N=1024), bf16 out ----------------
__global__ __launch_bounds__(256) void gemm_pre(const unsigned short* __restrict__ xb,
                                                const unsigned short* __restrict__ wxtb,
                                                const float* __restrict__ bias,
                                                unsigned short* __restrict__ pre) {
    int mb = blockIdx.x * 64;
    int nb = blockIdx.y * 64;
    int wave = threadIdx.x >> 6, lane = threadIdx.x & 63;
    int l15 = lane & 15, lkq = lane >> 4;

    f32x4 acc[4] = {};
    const unsigned short* aptr = xb + (size_t)(mb + wave * 16 + l15) * DIN + lkq * 8;
#pragma unroll
    for (int ks = 0; ks < DIN / 32; ++ks) {
        bf16x8 a = *(const bf16x8*)(aptr + ks * 32);
#pragma unroll
        for (int nt = 0; nt < 4; ++nt) {
            const unsigned short* bp =
                wxtb + (size_t)(nb + nt * 16 + l15) * DIN + ks * 32 + lkq * 8;
            bf16x8 b = *(const bf16x8*)bp;
            acc[nt] = __builtin_amdgcn_mfma_f32_16x16x32_bf16(a, b, acc[nt], 0, 0, 0);
        }
    }
#pragma unroll
    for (int nt = 0; nt < 4; ++nt) {
        int col = nb + nt * 16 + l15;
        float bb = bias[col];
#pragma unroll
        for (int r = 0; r < 4; ++r) {
            int row = mb + wave * 16 + lkq * 4 + r;
            pre[(size_t)row * HID + col] = f2bf(acc[nt][r] + bb);
        }
    }
}

// ---------------- persistent recurrence kernel ----------------
// grid = 64 blocks x 256 threads. Block k owns h columns [16k,16k+16).
// Wh slice pre-swizzled into LDS (B-fragment order) once.
// Per step: distributed-flag epoch barrier (relaxed polls + ONE acquire fence),
// h double-buffered in global bf16, normal vectorized loads/stores for payload.
__global__ __launch_bounds__(256, 1) void rnn_persistent(const float* __restrict__ Wh,
                                                         const unsigned short* __restrict__ pre,
                                                         unsigned short* __restrict__ hbuf,
                                                         unsigned* __restrict__ flags) {
    __shared__ unsigned short ldsB[32 * 64 * 8];  // 32 KB, [ks][lane][8 contiguous bf16]
    const int cb = blockIdx.x * 16;
    const int tid = threadIdx.x;

    // Stage + swizzle Wh[:, cb:cb+16) into B-frag layout (one time).
    for (int p = tid; p < 32 * 64; p += 256) {
        int ks = p >> 6, L = p & 63;
        int k0 = ks * 32 + ((L >> 4) * 8);
        int col = cb + (L & 15);
#pragma unroll
        for (int j = 0; j < 8; ++j)
            ldsB[p * 8 + j] = f2bf(Wh[(size_t)(k0 + j) * HID + col]);
    }
    __syncthreads();

    const int wave = tid >> 6, lane = tid & 63;
    const int l15 = lane & 15, lkq = lane >> 4;
    const int row0 = wave * 16;
    const int col = cb + l15;

    // t = 0: h1 = tanh(pre[0]) (h0 == 0), stored in buf[1]
    unsigned short* buf1 = hbuf + (size_t)BATCH * HID;
#pragma unroll
    for (int r = 0; r < 4; ++r) {
        int row = row0 + lkq * 4 + r;
        buf1[(size_t)row * HID + col] = f2bf(tanhf(bf2f(pre[(size_t)row * HID + col])));
    }
    __syncthreads();            // drains this block's h stores (vmcnt 0 before s_barrier)
    if (tid == 0) {
        __builtin_amdgcn_fence(__ATOMIC_RELEASE, "agent");  // wbl2: push h to L3
        __hip_atomic_store(&flags[blockIdx.x * FLAG_STRIDE], 1u,
                           __ATOMIC_RELAXED, __HIP_MEMORY_SCOPE_AGENT);
    }

    for (int t = 1; t <= 510; ++t) {
        const unsigned short* pt = pre + (size_t)t * BATCH * HID;

        // Prefetch this step's pre values into registers (independent of h_t).
        float pv[4];
#pragma unroll
        for (int r = 0; r < 4; ++r) {
            int row = row0 + lkq * 4 + r;
            pv[r] = bf2f(pt[(size_t)row * HID + col]);
        }

        // Wait until every block has published h_t. Relaxed coherent polls
        // (no cache maintenance per iteration), wave 0 only.
        if (tid < NBLK) {
            while (__hip_atomic_load(&flags[tid * FLAG_STRIDE],
                                     __ATOMIC_RELAXED, __HIP_MEMORY_SCOPE_AGENT) < (unsigned)t)
                __builtin_amdgcn_s_sleep(1);
        }
        __syncthreads();
        __builtin_amdgcn_fence(__ATOMIC_ACQUIRE, "agent");  // one inv per step

        const unsigned short* hc = hbuf + (size_t)(t & 1) * BATCH * HID;
        unsigned short* hn = hbuf + (size_t)((t + 1) & 1) * BATCH * HID;

        f32x4 acc0 = {}, acc1 = {};
        const unsigned short* ap = hc + (size_t)(row0 + l15) * HID + lkq * 8;
#pragma unroll
        for (int ks = 0; ks < 32; ks += 2) {
            bf16x8 a0 = *(const bf16x8*)(ap + ks * 32);
            bf16x8 b0 = *(const bf16x8*)&ldsB[((ks)*64 + lane) * 8];
            acc0 = __builtin_amdgcn_mfma_f32_16x16x32_bf16(a0, b0, acc0, 0, 0, 0);
            bf16x8 a1 = *(const bf16x8*)(ap + ks * 32 + 32);
            bf16x8 b1 = *(const bf16x8*)&ldsB[((ks + 1) * 64 + lane) * 8];
            acc1 = __builtin_amdgcn_mfma_f32_16x16x32_bf16(a1, b1, acc1, 0, 0, 0);
        }
        f32x4 acc = acc0 + acc1;

#pragma unroll
        for (int r = 0; r < 4; ++r) {
            int row = row0 + lkq * 4 + r;
            hn[(size_t)row * HID + col] = f2bf(tanhf(acc[r] + pv[r]));
        }

        if (t < 510) {
            __syncthreads();    // all waves' h stores drained (vmcnt 0 before barrier)
            if (tid == 0) {
                __builtin_amdgcn_fence(__ATOMIC_RELEASE, "agent");
                __hip_atomic_store(&flags[blockIdx.x * FLAG_STRIDE], (unsigned)(t + 1),
                                   __ATOMIC_RELAXED, __HIP_MEMORY_SCOPE_AGENT);
            }
        }
    }
    // h_511 (== H[-2]) sits in buf[1]; kernel end is an implicit device release.
}

// ---------------- y = h_final @ W2 + b2 ----------------
__global__ __launch_bounds__(256) void out_gemm(const unsigned short* __restrict__ hfin,
                                                const float* __restrict__ W2,
                                                const float* __restrict__ b2,
                                                float* __restrict__ out) {
    int b = blockIdx.x;        // 64
    int j = threadIdx.x;       // 256
    float acc = b2[j];
    const unsigned short* hr = hfin + (size_t)b * HID;
    for (int k = 0; k < HID; ++k)
        acc = fmaf(bf2f(hr[k]), W2[(size_t)k * DOUT + j], acc);
    out[(size_t)b * DOUT + j] = acc;
}

extern "C" void kernel_launch(void* const* d_in, const int* in_sizes, int n_in,
                              void* d_out, int out_size, void* d_ws, size_t ws_size,
                              hipStream_t stream) {
    const float* x  = (const float*)d_in[0];
    const float* Wx = (const float*)d_in[1];
    const float* Wh = (const float*)d_in[2];
    const float* b  = (const float*)d_in[3];
    const float* W2 = (const float*)d_in[4];
    const float* b2 = (const float*)d_in[5];
    float* out = (float*)d_out;

    // workspace carve (needs ~81 MB)
    char* ws = (char*)d_ws;
    unsigned*       flags = (unsigned*)ws;                                   // 4 KB
    unsigned short* hbuf  = (unsigned short*)(ws + 4096);                    // 256 KB
    unsigned short* xb    = (unsigned short*)(ws + 4096 + 2 * BATCH * HID * 2); // 16 MB
    unsigned short* wxtb  = xb + (size_t)T_STEPS * BATCH * DIN;              // 0.5 MB
    unsigned short* pre   = wxtb + (size_t)HID * DIN;                        // 64 MB

    (void)hipMemsetAsync(flags, 0, 4096, stream);
    convert_x<<<8192, 256, 0, stream>>>(x, xb);
    convert_wxt<<<1024, 256, 0, stream>>>(Wx, wxtb);
    gemm_pre<<<dim3(512, 16), 256, 0, stream>>>(xb, wxtb, b, pre);
    rnn_persistent<<<NBLK, 256, 0, stream>>>(Wh, pre, hbuf, flags);
    out_gemm<<<64, 256, 0, stream>>>(hbuf + (size_t)BATCH * HID, W2, b2, out);
}

// Round 4
// 4650.092 us; speedup vs baseline: 1.0489x; 1.0242x over previous
//
#include <hip/hip_runtime.h>
#include <hip/hip_bf16.h>
#include <math.h>

// Problem dims (fixed by reference)
#define T_STEPS 512
#define BATCH   64
#define DIN     256
#define HID     1024
#define DOUT    256
#define NBLK    64      // persistent blocks in recurrence (<= 256 CUs -> all co-resident)
#define FLAG_STRIDE 16  // flags padded to 64B lines

typedef __attribute__((ext_vector_type(8))) short    bf16x8;
typedef __attribute__((ext_vector_type(4))) float    f32x4;
typedef unsigned long long ull;

static __device__ __forceinline__ unsigned short f2bf(float f) {
    union { float f; unsigned u; } v; v.f = f;
    unsigned u = v.u;
    u += 0x7fff + ((u >> 16) & 1);   // round-to-nearest-even
    return (unsigned short)(u >> 16);
}
static __device__ __forceinline__ float bf2f(unsigned short h) {
    union { unsigned u; float f; } v; v.u = ((unsigned)h) << 16; return v.f;
}

// Coherent (cross-XCD) 8-byte load/store: agent-scope relaxed atomics lower to
// global_load/store_dwordx2 with sc0|sc1 -> bypass/write-through L2 to the
// Infinity Cache coherence point. NO wbl2/inv cache walks anywhere.
static __device__ __forceinline__ ull coh_load(const ull* p) {
    return __hip_atomic_load(p, __ATOMIC_RELAXED, __HIP_MEMORY_SCOPE_AGENT);
}
static __device__ __forceinline__ void coh_store(ull* p, ull v) {
    __hip_atomic_store(p, v, __ATOMIC_RELAXED, __HIP_MEMORY_SCOPE_AGENT);
}

// ---------------- convert kernels ----------------
__global__ __launch_bounds__(256) void convert_x(const float* __restrict__ x,
                                                 unsigned short* __restrict__ xb) {
    size_t i = ((size_t)blockIdx.x * 256 + threadIdx.x) * 4;
    float4 v = *(const float4*)(x + i);
    ushort4 o;
    o.x = f2bf(v.x); o.y = f2bf(v.y); o.z = f2bf(v.z); o.w = f2bf(v.w);
    *(ushort4*)(xb + i) = o;
}

__global__ __launch_bounds__(256) void convert_wxt(const float* __restrict__ Wx,
                                                   unsigned short* __restrict__ wxtb) {
    // Wx[DIN][HID] fp32 -> WxT[HID][DIN] bf16 (coalesced write)
    int o = blockIdx.x * 256 + threadIdx.x;  // 262144 total
    int d = o & (DIN - 1);
    int j = o >> 8;
    wxtb[(size_t)j * DIN + d] = f2bf(Wx[(size_t)d * HID + j]);
}

// ---------------- pre = x @ Wx + b  (M=32768, K=256, N=1024), bf16 out ----------------
__global__ __launch_bounds__(256) void gemm_pre(const unsigned short* __restrict__ xb,
                                                const unsigned short* __restrict__ wxtb,
                                                const float* __restrict__ bias,
                                                unsigned short* __restrict__ pre) {
    int mb = blockIdx.x * 64;
    int nb = blockIdx.y * 64;
    int wave = threadIdx.x >> 6, lane = threadIdx.x & 63;
    int l15 = lane & 15, lkq = lane >> 4;

    f32x4 acc[4] = {};
    const unsigned short* aptr = xb + (size_t)(mb + wave * 16 + l15) * DIN + lkq * 8;
#pragma unroll
    for (int ks = 0; ks < DIN / 32; ++ks) {
        bf16x8 a = *(const bf16x8*)(aptr + ks * 32);
#pragma unroll
        for (int nt = 0; nt < 4; ++nt) {
            const unsigned short* bp =
                wxtb + (size_t)(nb + nt * 16 + l15) * DIN + ks * 32 + lkq * 8;
            bf16x8 b = *(const bf16x8*)bp;
            acc[nt] = __builtin_amdgcn_mfma_f32_16x16x32_bf16(a, b, acc[nt], 0, 0, 0);
        }
    }
#pragma unroll
    for (int nt = 0; nt < 4; ++nt) {
        int col = nb + nt * 16 + l15;
        float bb = bias[col];
#pragma unroll
        for (int r = 0; r < 4; ++r) {
            int row = mb + wave * 16 + lkq * 4 + r;
            pre[(size_t)row * HID + col] = f2bf(acc[nt][r] + bb);
        }
    }
}

// ---------------- persistent recurrence kernel ----------------
// grid = 64 blocks x 256 threads. Block k owns h columns [16k,16k+16).
// Wh slice pre-swizzled into LDS (B-fragment order) once.
// Cross-block h exchange is done ENTIRELY with L2-bypassing coherent 8-byte
// atomic loads/stores (write-through to Infinity Cache). No fences in the loop
// -> no buffer_wbl2 / buffer_inv cache walks (the Round-1/3 8.8us/step cost).
__global__ __launch_bounds__(256, 1) void rnn_persistent(const float* __restrict__ Wh,
                                                         const unsigned short* __restrict__ pre,
                                                         unsigned short* __restrict__ hbuf,
                                                         unsigned* __restrict__ flags) {
    __shared__ unsigned short ldsB[32 * 64 * 8];  // 32 KB, [ks][lane][8 contiguous bf16]
    __shared__ unsigned short ldsC[64 * 16];      // 2 KB C-fragment staging
    const int cb = blockIdx.x * 16;
    const int tid = threadIdx.x;

    // Stage + swizzle Wh[:, cb:cb+16) into B-frag layout (one time).
    for (int p = tid; p < 32 * 64; p += 256) {
        int ks = p >> 6, L = p & 63;
        int k0 = ks * 32 + ((L >> 4) * 8);
        int col = cb + (L & 15);
#pragma unroll
        for (int j = 0; j < 8; ++j)
            ldsB[p * 8 + j] = f2bf(Wh[(size_t)(k0 + j) * HID + col]);
    }

    const int wave = tid >> 6, lane = tid & 63;
    const int l15 = lane & 15, lkq = lane >> 4;
    const int row0 = wave * 16;

    // t = 0: h1 = tanh(pre[0]) (h0 == 0) -> coherent stores into buf[1].
    // One 8B chunk per thread: 64 rows x 16 cols x 2B = 2 KB = 256 chunks.
    {
        int row = tid >> 2, sub = tid & 3;
        size_t el = (size_t)row * HID + cb + sub * 4;
        union { ushort4 s; ull u; } in, ov;
        in.s = *(const ushort4*)(pre + el);
        ov.s.x = f2bf(tanhf(bf2f(in.s.x)));
        ov.s.y = f2bf(tanhf(bf2f(in.s.y)));
        ov.s.z = f2bf(tanhf(bf2f(in.s.z)));
        ov.s.w = f2bf(tanhf(bf2f(in.s.w)));
        ull* b1 = (ull*)(hbuf + (size_t)BATCH * HID);
        coh_store(&b1[el >> 2], ov.u);
    }
    __syncthreads();   // drains stores (vmcnt 0 before s_barrier); also covers ldsB staging
    if (tid == 0)
        __hip_atomic_store(&flags[blockIdx.x * FLAG_STRIDE], 1u,
                           __ATOMIC_RELAXED, __HIP_MEMORY_SCOPE_AGENT);

    for (int t = 1; t <= 510; ++t) {
        const unsigned short* pt = pre + (size_t)t * BATCH * HID;

        // Prefetch this step's pre values (independent of h_t) behind the poll.
        float pv[4];
#pragma unroll
        for (int r = 0; r < 4; ++r)
            pv[r] = bf2f(pt[(size_t)(row0 + lkq * 4 + r) * HID + cb + l15]);

        // Wait until every block has published h_t (relaxed coherent polls).
        if (tid < NBLK) {
            while (__hip_atomic_load(&flags[tid * FLAG_STRIDE],
                                     __ATOMIC_RELAXED, __HIP_MEMORY_SCOPE_AGENT) < (unsigned)t)
                __builtin_amdgcn_s_sleep(1);
        }
        __syncthreads();

        const ull* hc = (const ull*)(hbuf + (size_t)(t & 1) * BATCH * HID);
        ull*       hn = (ull*)(hbuf + (size_t)((t + 1) & 1) * BATCH * HID);

        // A-fragment: h[row0+l15][ks*32 + lkq*8 .. +8) = 16B = two coherent 8B loads.
        f32x4 acc0 = {}, acc1 = {};
        const ull* ap = hc + (((size_t)(row0 + l15) * HID + lkq * 8) >> 2);
#pragma unroll
        for (int ks = 0; ks < 32; ks += 2) {
            union { ull u[2]; bf16x8 v; } a0, a1;
            a0.u[0] = coh_load(ap + ks * 8);
            a0.u[1] = coh_load(ap + ks * 8 + 1);
            a1.u[0] = coh_load(ap + ks * 8 + 8);
            a1.u[1] = coh_load(ap + ks * 8 + 9);
            bf16x8 w0 = *(const bf16x8*)&ldsB[((ks)*64 + lane) * 8];
            bf16x8 w1 = *(const bf16x8*)&ldsB[((ks + 1) * 64 + lane) * 8];
            acc0 = __builtin_amdgcn_mfma_f32_16x16x32_bf16(a0.v, w0, acc0, 0, 0, 0);
            acc1 = __builtin_amdgcn_mfma_f32_16x16x32_bf16(a1.v, w1, acc1, 0, 0, 0);
        }
        f32x4 acc = acc0 + acc1;

        // Epilogue: tanh, stage C-frag (column-strided) into LDS tile [64][16].
#pragma unroll
        for (int r = 0; r < 4; ++r)
            ldsC[(row0 + lkq * 4 + r) * 16 + l15] = f2bf(tanhf(acc[r] + pv[r]));
        __syncthreads();

        // Packed coherent stores: one 8B chunk per thread.
        {
            int row = tid >> 2, sub = tid & 3;
            ull v = ((const ull*)ldsC)[tid];
            coh_store(&hn[(size_t)row * (HID / 4) + (cb >> 2) + sub], v);
        }

        if (t < 510) {
            __syncthreads();    // vmcnt(0) drain before barrier -> stores visible at L3
            if (tid == 0)
                __hip_atomic_store(&flags[blockIdx.x * FLAG_STRIDE], (unsigned)(t + 1),
                                   __ATOMIC_RELAXED, __HIP_MEMORY_SCOPE_AGENT);
        }
    }
    // h_511 (== H[-2]) is in buf[1]; kernel end is an implicit device release.
}

// ---------------- y = h_final @ W2 + b2 ----------------
__global__ __launch_bounds__(256) void out_gemm(const unsigned short* __restrict__ hfin,
                                                const float* __restrict__ W2,
                                                const float* __restrict__ b2,
                                                float* __restrict__ out) {
    int b = blockIdx.x;        // 64
    int j = threadIdx.x;       // 256
    float acc = b2[j];
    const unsigned short* hr = hfin + (size_t)b * HID;
    for (int k = 0; k < HID; ++k)
        acc = fmaf(bf2f(hr[k]), W2[(size_t)k * DOUT + j], acc);
    out[(size_t)b * DOUT + j] = acc;
}

extern "C" void kernel_launch(void* const* d_in, const int* in_sizes, int n_in,
                              void* d_out, int out_size, void* d_ws, size_t ws_size,
                              hipStream_t stream) {
    const float* x  = (const float*)d_in[0];
    const float* Wx = (const float*)d_in[1];
    const float* Wh = (const float*)d_in[2];
    const float* b  = (const float*)d_in[3];
    const float* W2 = (const float*)d_in[4];
    const float* b2 = (const float*)d_in[5];
    float* out = (float*)d_out;

    // workspace carve (needs ~81 MB)
    char* ws = (char*)d_ws;
    unsigned*       flags = (unsigned*)ws;                                   // 4 KB
    unsigned short* hbuf  = (unsigned short*)(ws + 4096);                    // 256 KB
    unsigned short* xb    = (unsigned short*)(ws + 4096 + 2 * BATCH * HID * 2); // 16 MB
    unsigned short* wxtb  = xb + (size_t)T_STEPS * BATCH * DIN;              // 0.5 MB
    unsigned short* pre   = wxtb + (size_t)HID * DIN;                        // 64 MB

    (void)hipMemsetAsync(flags, 0, 4096, stream);
    convert_x<<<8192, 256, 0, stream>>>(x, xb);
    convert_wxt<<<1024, 256, 0, stream>>>(Wx, wxtb);
    gemm_pre<<<dim3(512, 16), 256, 0, stream>>>(xb, wxtb, b, pre);
    rnn_persistent<<<NBLK, 256, 0, stream>>>(Wh, pre, hbuf, flags);
    out_gemm<<<64, 256, 0, stream>>>(hbuf + (size_t)BATCH * HID, W2, b2, out);
}

// Round 5
// 3744.679 us; speedup vs baseline: 1.3026x; 1.2418x over previous
//
#include <hip/hip_runtime.h>
#include <hip/hip_bf16.h>
#include <math.h>

// Problem dims (fixed by reference)
#define T_STEPS 512
#define BATCH   64
#define DIN     256
#define HID     1024
#define DOUT    256
#define NBLK    64      // persistent blocks in recurrence (<= 256 CUs -> all co-resident)
#define FLAG_STRIDE 16  // flags padded to 64B lines

typedef __attribute__((ext_vector_type(8))) short    bf16x8;
typedef __attribute__((ext_vector_type(4))) float    f32x4;
typedef unsigned long long ull;

static __device__ __forceinline__ unsigned short f2bf(float f) {
    union { float f; unsigned u; } v; v.f = f;
    unsigned u = v.u;
    u += 0x7fff + ((u >> 16) & 1);   // round-to-nearest-even
    return (unsigned short)(u >> 16);
}
static __device__ __forceinline__ float bf2f(unsigned short h) {
    union { unsigned u; float f; } v; v.u = ((unsigned)h) << 16; return v.f;
}

// Coherent (cross-XCD) ops: agent-scope relaxed atomics lower to sc0|sc1
// (write-through / L2-bypass to the MALL coherence point). Proven correct in R4.
static __device__ __forceinline__ void coh_store8(ull* p, ull v) {
    __hip_atomic_store(p, v, __ATOMIC_RELAXED, __HIP_MEMORY_SCOPE_AGENT);
}

// ---------------- convert kernels ----------------
__global__ __launch_bounds__(256) void convert_x(const float* __restrict__ x,
                                                 unsigned short* __restrict__ xb) {
    size_t i = ((size_t)blockIdx.x * 256 + threadIdx.x) * 4;
    float4 v = *(const float4*)(x + i);
    ushort4 o;
    o.x = f2bf(v.x); o.y = f2bf(v.y); o.z = f2bf(v.z); o.w = f2bf(v.w);
    *(ushort4*)(xb + i) = o;
}

__global__ __launch_bounds__(256) void convert_wxt(const float* __restrict__ Wx,
                                                   unsigned short* __restrict__ wxtb) {
    // Wx[DIN][HID] fp32 -> WxT[HID][DIN] bf16 (coalesced write)
    int o = blockIdx.x * 256 + threadIdx.x;  // 262144 total
    int d = o & (DIN - 1);
    int j = o >> 8;
    wxtb[(size_t)j * DIN + d] = f2bf(Wx[(size_t)d * HID + j]);
}

// ---------------- pre = x @ Wx + b, written in CONSUMER FRAGMENT LAYOUT ----------
// pre_r is indexed in 8-byte units: [t][blk][wave][lane] where each chunk holds
// the 4 bf16 values {pre[t][wave*16 + (lane>>4)*4 + r][blk*16 + (lane&15)]}.
// The rnn kernel then reads its whole per-step pre slice with ONE ull load/thread.
__global__ __launch_bounds__(256) void gemm_pre(const unsigned short* __restrict__ xb,
                                                const unsigned short* __restrict__ wxtb,
                                                const float* __restrict__ bias,
                                                ull* __restrict__ pre_r) {
    int t  = blockIdx.x;            // 512 blocks: rows [t*64, t*64+64) = timestep t
    int nb = blockIdx.y * 64;
    int wave = threadIdx.x >> 6, lane = threadIdx.x & 63;
    int l15 = lane & 15, lkq = lane >> 4;

    f32x4 acc[4] = {};
    const unsigned short* aptr = xb + (size_t)(t * 64 + wave * 16 + l15) * DIN + lkq * 8;
#pragma unroll
    for (int ks = 0; ks < DIN / 32; ++ks) {
        bf16x8 a = *(const bf16x8*)(aptr + ks * 32);
#pragma unroll
        for (int nt = 0; nt < 4; ++nt) {
            const unsigned short* bp =
                wxtb + (size_t)(nb + nt * 16 + l15) * DIN + ks * 32 + lkq * 8;
            bf16x8 b = *(const bf16x8*)bp;
            acc[nt] = __builtin_amdgcn_mfma_f32_16x16x32_bf16(a, b, acc[nt], 0, 0, 0);
        }
    }
#pragma unroll
    for (int nt = 0; nt < 4; ++nt) {
        int blk = blockIdx.y * 4 + nt;
        float bb = bias[blk * 16 + l15];
        union { ushort4 s; ull u; } o;
        o.s.x = f2bf(acc[nt][0] + bb);
        o.s.y = f2bf(acc[nt][1] + bb);
        o.s.z = f2bf(acc[nt][2] + bb);
        o.s.w = f2bf(acc[nt][3] + bb);
        // 64 lanes write 64 consecutive 8B chunks -> fully coalesced 512B/wave
        pre_r[(((size_t)(t * 64 + blk) * 4 + wave) * 64 + lane)] = o.u;
    }
}

// ---------------- persistent recurrence kernel ----------------
// grid = 64 blocks x 256 threads. Block k owns h columns [16k,16k+16).
// Per step: poll flags (sc1) -> ONE acquire fence (buffer_inv, no wbl2 since h
// is never dirty in L2) -> cached b128 h import -> MFMA -> tanh -> ldsC repack
// -> sc1 write-through h stores -> syncthreads (vmcnt drain) -> sc1 flag store.
// pre arrives as one 8B register-pipelined load per thread (off critical path).
__global__ __launch_bounds__(256, 1) void rnn_persistent(const float* __restrict__ Wh,
                                                         const ull* __restrict__ pre_r,
                                                         unsigned short* __restrict__ hbuf,
                                                         unsigned* __restrict__ flags) {
    __shared__ unsigned short ldsB[32 * 64 * 8];  // 32 KB, Wh B-frags
    __shared__ unsigned short ldsC[64 * 16];      // 2 KB C-frag repack
    const int cb = blockIdx.x * 16;
    const int tid = threadIdx.x;

    // Stage + swizzle Wh[:, cb:cb+16) into B-frag layout (one time).
    for (int p = tid; p < 32 * 64; p += 256) {
        int ks = p >> 6, L = p & 63;
        int k0 = ks * 32 + ((L >> 4) * 8);
        int col = cb + (L & 15);
#pragma unroll
        for (int j = 0; j < 8; ++j)
            ldsB[p * 8 + j] = f2bf(Wh[(size_t)(k0 + j) * HID + col]);
    }

    const int wave = tid >> 6, lane = tid & 63;
    const int l15 = lane & 15, lkq = lane >> 4;
    const int row0 = wave * 16;

    // Per-thread pre_r address for step t: ((t*64 + blk)*4 + wave)*64 + lane
    const ull* myPre = pre_r + ((size_t)blockIdx.x * 4 + wave) * 64 + lane;
#define PRE_AT(t) myPre[(size_t)(t) * 64 * 4 * 64]

    // t = 0: h1 = tanh(pre[0]) (h0 == 0) via the standard epilogue path.
    {
        union { ushort4 s; ull u; } pv; pv.u = PRE_AT(0);
        float v0 = tanhf(bf2f(pv.s.x)), v1 = tanhf(bf2f(pv.s.y));
        float v2 = tanhf(bf2f(pv.s.z)), v3 = tanhf(bf2f(pv.s.w));
        ldsC[(row0 + lkq * 4 + 0) * 16 + l15] = f2bf(v0);
        ldsC[(row0 + lkq * 4 + 1) * 16 + l15] = f2bf(v1);
        ldsC[(row0 + lkq * 4 + 2) * 16 + l15] = f2bf(v2);
        ldsC[(row0 + lkq * 4 + 3) * 16 + l15] = f2bf(v3);
    }
    __syncthreads();
    {
        int row = tid >> 2, sub = tid & 3;
        ull* b1 = (ull*)(hbuf + (size_t)BATCH * HID);
        coh_store8(&b1[(size_t)row * (HID / 4) + blockIdx.x * 4 + sub],
                   ((const ull*)ldsC)[tid]);
    }
    __syncthreads();   // all waves' sc1 stores vmcnt-drained before flag
    if (tid == 0)
        __hip_atomic_store(&flags[blockIdx.x * FLAG_STRIDE], 1u,
                           __ATOMIC_RELAXED, __HIP_MEMORY_SCOPE_AGENT);

    // Software-pipelined pre fetch: pv_next holds step-1 data entering the loop.
    ull pv_next = PRE_AT(1);

    for (int t = 1; t <= 510; ++t) {
        union { ushort4 s; ull u; } pvc; pvc.u = pv_next;
        if (t < 510) pv_next = PRE_AT(t + 1);   // off critical path (read-only data)

        // Wait until every block has published h_t (sc1 relaxed polls, wave 0).
        if (tid < NBLK) {
            while (__hip_atomic_load(&flags[tid * FLAG_STRIDE],
                                     __ATOMIC_RELAXED, __HIP_MEMORY_SCOPE_AGENT) < (unsigned)t)
                __builtin_amdgcn_s_sleep(1);
        }
        __syncthreads();
        // One L2/L1 invalidate per step: makes the write-through h_t visible to
        // the cached imports below. No release/wbl2 anywhere (h never dirty).
        __builtin_amdgcn_fence(__ATOMIC_ACQUIRE, "agent");

        const unsigned short* hc = hbuf + (size_t)(t & 1) * BATCH * HID;
        ull* hn = (ull*)(hbuf + (size_t)((t + 1) & 1) * BATCH * HID);

        // Cached line-granular import + MFMA (compiler pipelines the b128 loads).
        f32x4 acc0 = {}, acc1 = {};
        const unsigned short* ap = hc + (size_t)(row0 + l15) * HID + lkq * 8;
#pragma unroll
        for (int ks = 0; ks < 32; ks += 2) {
            bf16x8 a0 = *(const bf16x8*)(ap + ks * 32);
            bf16x8 w0 = *(const bf16x8*)&ldsB[((ks)*64 + lane) * 8];
            acc0 = __builtin_amdgcn_mfma_f32_16x16x32_bf16(a0, w0, acc0, 0, 0, 0);
            bf16x8 a1 = *(const bf16x8*)(ap + ks * 32 + 32);
            bf16x8 w1 = *(const bf16x8*)&ldsB[((ks + 1) * 64 + lane) * 8];
            acc1 = __builtin_amdgcn_mfma_f32_16x16x32_bf16(a1, w1, acc1, 0, 0, 0);
        }
        f32x4 acc = acc0 + acc1;

        // Epilogue: add pre (register), tanh, repack via LDS, coherent 8B stores.
        ldsC[(row0 + lkq * 4 + 0) * 16 + l15] = f2bf(tanhf(acc[0] + bf2f(pvc.s.x)));
        ldsC[(row0 + lkq * 4 + 1) * 16 + l15] = f2bf(tanhf(acc[1] + bf2f(pvc.s.y)));
        ldsC[(row0 + lkq * 4 + 2) * 16 + l15] = f2bf(tanhf(acc[2] + bf2f(pvc.s.z)));
        ldsC[(row0 + lkq * 4 + 3) * 16 + l15] = f2bf(tanhf(acc[3] + bf2f(pvc.s.w)));
        __syncthreads();
        {
            int row = tid >> 2, sub = tid & 3;
            coh_store8(&hn[(size_t)row * (HID / 4) + blockIdx.x * 4 + sub],
                       ((const ull*)ldsC)[tid]);
        }

        if (t < 510) {
            __syncthreads();    // vmcnt(0) drain -> h_{t+1} at coherence point
            if (tid == 0)
                __hip_atomic_store(&flags[blockIdx.x * FLAG_STRIDE], (unsigned)(t + 1),
                                   __ATOMIC_RELAXED, __HIP_MEMORY_SCOPE_AGENT);
        }
    }
    // h_511 (== H[-2]) is in buf[1]; kernel end is an implicit device release.
#undef PRE_AT
}

// ---------------- y = h_final @ W2 + b2 ----------------
__global__ __launch_bounds__(256) void out_gemm(const unsigned short* __restrict__ hfin,
                                                const float* __restrict__ W2,
                                                const float* __restrict__ b2,
                                                float* __restrict__ out) {
    int b = blockIdx.x;        // 64
    int j = threadIdx.x;       // 256
    float acc = b2[j];
    const unsigned short* hr = hfin + (size_t)b * HID;
    for (int k = 0; k < HID; ++k)
        acc = fmaf(bf2f(hr[k]), W2[(size_t)k * DOUT + j], acc);
    out[(size_t)b * DOUT + j] = acc;
}

extern "C" void kernel_launch(void* const* d_in, const int* in_sizes, int n_in,
                              void* d_out, int out_size, void* d_ws, size_t ws_size,
                              hipStream_t stream) {
    const float* x  = (const float*)d_in[0];
    const float* Wx = (const float*)d_in[1];
    const float* Wh = (const float*)d_in[2];
    const float* b  = (const float*)d_in[3];
    const float* W2 = (const float*)d_in[4];
    const float* b2 = (const float*)d_in[5];
    float* out = (float*)d_out;

    // workspace carve (~81 MB)
    char* ws = (char*)d_ws;
    unsigned*       flags = (unsigned*)ws;                                   // 4 KB
    unsigned short* hbuf  = (unsigned short*)(ws + 4096);                    // 256 KB
    unsigned short* xb    = (unsigned short*)(ws + 4096 + 2 * BATCH * HID * 2); // 16 MB
    unsigned short* wxtb  = xb + (size_t)T_STEPS * BATCH * DIN;              // 0.5 MB
    ull*            pre_r = (ull*)(wxtb + (size_t)HID * DIN);                // 64 MB

    (void)hipMemsetAsync(flags, 0, 4096, stream);
    convert_x<<<8192, 256, 0, stream>>>(x, xb);
    convert_wxt<<<1024, 256, 0, stream>>>(Wx, wxtb);
    gemm_pre<<<dim3(512, 16), 256, 0, stream>>>(xb, wxtb, b, pre_r);
    rnn_persistent<<<NBLK, 256, 0, stream>>>(Wh, pre_r, hbuf, flags);
    out_gemm<<<64, 256, 0, stream>>>(hbuf + (size_t)BATCH * HID, W2, b2, out);
}

// Round 6
// 2285.946 us; speedup vs baseline: 2.1337x; 1.6381x over previous
//
#include <hip/hip_runtime.h>
#include <hip/hip_bf16.h>
#include <math.h>

// Problem dims (fixed by reference)
#define T_STEPS 512
#define BATCH   64
#define DIN     256
#define HID     1024
#define DOUT    256
#define NBLK    64      // persistent blocks in recurrence (<= 256 CUs -> all co-resident)
#define FLAG_STRIDE 16  // flags padded to 64B lines

typedef __attribute__((ext_vector_type(8))) short    bf16x8;
typedef __attribute__((ext_vector_type(4))) float    f32x4;
typedef unsigned long long ull;

static __device__ __forceinline__ unsigned short f2bf(float f) {
    union { float f; unsigned u; } v; v.f = f;
    unsigned u = v.u;
    u += 0x7fff + ((u >> 16) & 1);   // round-to-nearest-even
    return (unsigned short)(u >> 16);
}
static __device__ __forceinline__ float bf2f(unsigned short h) {
    union { unsigned u; float f; } v; v.u = ((unsigned)h) << 16; return v.f;
}

// Coherent (cross-XCD) 8B ops: agent-scope relaxed atomics lower to sc0|sc1
// (L2-bypass / write-through to the MALL coherence point). Correctness of the
// fence-free store->syncthreads->flag / sc1-load protocol was proven in R4.
static __device__ __forceinline__ ull coh_load8(const ull* p) {
    return __hip_atomic_load(p, __ATOMIC_RELAXED, __HIP_MEMORY_SCOPE_AGENT);
}
static __device__ __forceinline__ void coh_store8(ull* p, ull v) {
    __hip_atomic_store(p, v, __ATOMIC_RELAXED, __HIP_MEMORY_SCOPE_AGENT);
}

// ---- h buffer A-fragment layout ----
// 16B chunk index (g,ks,lkq,m) = ((g*32+ks)<<6) + (lkq<<4) + m
// holds h[g*16 + m][ks*32 + lkq*8 .. +8).  (g: row group, m: row-in-group)
// Consumer wave w at slice ks: lane l reads chunk ((w*32+ks)<<6)+l  -> coalesced.

// ---------------- convert kernels ----------------
__global__ __launch_bounds__(256) void convert_x(const float* __restrict__ x,
                                                 unsigned short* __restrict__ xb) {
    size_t i = ((size_t)blockIdx.x * 256 + threadIdx.x) * 4;
    float4 v = *(const float4*)(x + i);
    ushort4 o;
    o.x = f2bf(v.x); o.y = f2bf(v.y); o.z = f2bf(v.z); o.w = f2bf(v.w);
    *(ushort4*)(xb + i) = o;
}

__global__ __launch_bounds__(256) void convert_wxt(const float* __restrict__ Wx,
                                                   unsigned short* __restrict__ wxtb) {
    // Wx[DIN][HID] fp32 -> WxT[HID][DIN] bf16 (coalesced write)
    int o = blockIdx.x * 256 + threadIdx.x;  // 262144 total
    int d = o & (DIN - 1);
    int j = o >> 8;
    wxtb[(size_t)j * DIN + d] = f2bf(Wx[(size_t)d * HID + j]);
}

// ---------------- pre = x @ Wx + b, written in CONSUMER FRAGMENT LAYOUT ----------
// pre_r 8B units: [t][blk][wave][lane] holding the 4 bf16 acc-row values.
__global__ __launch_bounds__(256) void gemm_pre(const unsigned short* __restrict__ xb,
                                                const unsigned short* __restrict__ wxtb,
                                                const float* __restrict__ bias,
                                                ull* __restrict__ pre_r) {
    int t  = blockIdx.x;            // timestep t = rows [t*64, t*64+64)
    int nb = blockIdx.y * 64;
    int wave = threadIdx.x >> 6, lane = threadIdx.x & 63;
    int l15 = lane & 15, lkq = lane >> 4;

    f32x4 acc[4] = {};
    const unsigned short* aptr = xb + (size_t)(t * 64 + wave * 16 + l15) * DIN + lkq * 8;
#pragma unroll
    for (int ks = 0; ks < DIN / 32; ++ks) {
        bf16x8 a = *(const bf16x8*)(aptr + ks * 32);
#pragma unroll
        for (int nt = 0; nt < 4; ++nt) {
            const unsigned short* bp =
                wxtb + (size_t)(nb + nt * 16 + l15) * DIN + ks * 32 + lkq * 8;
            bf16x8 b = *(const bf16x8*)bp;
            acc[nt] = __builtin_amdgcn_mfma_f32_16x16x32_bf16(a, b, acc[nt], 0, 0, 0);
        }
    }
#pragma unroll
    for (int nt = 0; nt < 4; ++nt) {
        int blk = blockIdx.y * 4 + nt;
        float bb = bias[blk * 16 + l15];
        union { ushort4 s; ull u; } o;
        o.s.x = f2bf(acc[nt][0] + bb);
        o.s.y = f2bf(acc[nt][1] + bb);
        o.s.z = f2bf(acc[nt][2] + bb);
        o.s.w = f2bf(acc[nt][3] + bb);
        pre_r[(((size_t)(t * 64 + blk) * 4 + wave) * 64 + lane)] = o.u;
    }
}

// ---------------- persistent recurrence kernel ----------------
// grid = 64 blocks x 256 threads. Block k owns h columns [16k,16k+16).
// FENCE-FREE loop: h exchanged via coalesced sc1 8B atomics in A-fragment
// layout; ordering = sc1 stores -> syncthreads (vmcnt drain) -> sc1 flag store.
__global__ __launch_bounds__(256, 1) void rnn_persistent(const float* __restrict__ Wh,
                                                         const ull* __restrict__ pre_r,
                                                         unsigned short* __restrict__ hbuf,
                                                         unsigned* __restrict__ flags) {
    __shared__ unsigned short ldsB[32 * 64 * 8];  // 32 KB, Wh B-frags
    __shared__ unsigned short ldsC[64 * 16];      // 2 KB C-frag repack
    const int cb = blockIdx.x * 16;
    const int bx = blockIdx.x;
    const int tid = threadIdx.x;

    // Stage + swizzle Wh[:, cb:cb+16) into B-frag layout (one time).
    for (int p = tid; p < 32 * 64; p += 256) {
        int ks = p >> 6, L = p & 63;
        int k0 = ks * 32 + ((L >> 4) * 8);
        int col = cb + (L & 15);
#pragma unroll
        for (int j = 0; j < 8; ++j)
            ldsB[p * 8 + j] = f2bf(Wh[(size_t)(k0 + j) * HID + col]);
    }

    const int w = tid >> 6, lane = tid & 63;
    const int l15 = lane & 15, lkq = lane >> 4;
    const int row0 = w * 16;

    // Per-thread h-store target (8B unit) in A-fragment layout:
    // g=tid>>6, ks=bx>>1, lkq=(bx&1)*2+((tid>>1)&1), m=(tid>>2)&15, half=tid&1
    const size_t st_unit =
        (((((size_t)(tid >> 6) * 32 + (bx >> 1)) << 6) +
          ((((bx & 1) * 2 + ((tid >> 1) & 1)) << 4) + ((tid >> 2) & 15))) << 1) + (tid & 1);

    // Per-thread pre_r address for step t
    const ull* myPre = pre_r + ((size_t)bx * 4 + w) * 64 + lane;
#define PRE_AT(t) myPre[(size_t)(t) * 64 * 4 * 64]

    // t = 0: h1 = tanh(pre[0]) (h0 == 0) via the standard epilogue path.
    {
        union { ushort4 s; ull u; } pv; pv.u = PRE_AT(0);
        ldsC[(row0 + lkq * 4 + 0) * 16 + l15] = f2bf(tanhf(bf2f(pv.s.x)));
        ldsC[(row0 + lkq * 4 + 1) * 16 + l15] = f2bf(tanhf(bf2f(pv.s.y)));
        ldsC[(row0 + lkq * 4 + 2) * 16 + l15] = f2bf(tanhf(bf2f(pv.s.z)));
        ldsC[(row0 + lkq * 4 + 3) * 16 + l15] = f2bf(tanhf(bf2f(pv.s.w)));
    }
    __syncthreads();
    coh_store8((ull*)(hbuf + (size_t)BATCH * HID) + st_unit, ((const ull*)ldsC)[tid]);
    __syncthreads();   // all waves' sc1 stores vmcnt-drained before flag
    if (tid == 0)
        __hip_atomic_store(&flags[bx * FLAG_STRIDE], 1u,
                           __ATOMIC_RELAXED, __HIP_MEMORY_SCOPE_AGENT);

    ull pv_next = PRE_AT(1);

    for (int t = 1; t <= 510; ++t) {
        union { ushort4 s; ull u; } pvc; pvc.u = pv_next;
        if (t < 510) pv_next = PRE_AT(t + 1);   // read-only, off critical path

        // Wait until every block has published h_t (sc1 relaxed polls, wave 0).
        if (tid < NBLK) {
            while (__hip_atomic_load(&flags[tid * FLAG_STRIDE],
                                     __ATOMIC_RELAXED, __HIP_MEMORY_SCOPE_AGENT) < (unsigned)t)
                __builtin_amdgcn_s_sleep(1);
        }
        __syncthreads();
        // NO fence: h_t arrives via L2-bypassing coalesced sc1 loads below.

        const ull* hcu = (const ull*)(hbuf + (size_t)(t & 1) * BATCH * HID);
        ull*       hnu = (ull*)(hbuf + (size_t)((t + 1) & 1) * BATCH * HID);

        // A-frag import: wave w, slice ks -> lane-consecutive 16B chunks.
        const ull* au = hcu + (((size_t)w * 32) << 7) + lane * 2;
        f32x4 acc0 = {}, acc1 = {};
#pragma unroll
        for (int ks = 0; ks < 32; ks += 2) {
            union { ull u[2]; bf16x8 v; } a0, a1;
            a0.u[0] = coh_load8(au + ((size_t)ks << 7));
            a0.u[1] = coh_load8(au + ((size_t)ks << 7) + 1);
            a1.u[0] = coh_load8(au + ((size_t)(ks + 1) << 7));
            a1.u[1] = coh_load8(au + ((size_t)(ks + 1) << 7) + 1);
            bf16x8 w0 = *(const bf16x8*)&ldsB[((ks)*64 + lane) * 8];
            bf16x8 w1 = *(const bf16x8*)&ldsB[((ks + 1) * 64 + lane) * 8];
            acc0 = __builtin_amdgcn_mfma_f32_16x16x32_bf16(a0.v, w0, acc0, 0, 0, 0);
            acc1 = __builtin_amdgcn_mfma_f32_16x16x32_bf16(a1.v, w1, acc1, 0, 0, 0);
        }
        f32x4 acc = acc0 + acc1;

        // Epilogue: add pre, tanh, repack via LDS, coalesced sc1 stores.
        ldsC[(row0 + lkq * 4 + 0) * 16 + l15] = f2bf(tanhf(acc[0] + bf2f(pvc.s.x)));
        ldsC[(row0 + lkq * 4 + 1) * 16 + l15] = f2bf(tanhf(acc[1] + bf2f(pvc.s.y)));
        ldsC[(row0 + lkq * 4 + 2) * 16 + l15] = f2bf(tanhf(acc[2] + bf2f(pvc.s.z)));
        ldsC[(row0 + lkq * 4 + 3) * 16 + l15] = f2bf(tanhf(acc[3] + bf2f(pvc.s.w)));
        __syncthreads();
        coh_store8(hnu + st_unit, ((const ull*)ldsC)[tid]);

        if (t < 510) {
            __syncthreads();    // vmcnt(0) drain -> h_{t+1} at coherence point
            if (tid == 0)
                __hip_atomic_store(&flags[bx * FLAG_STRIDE], (unsigned)(t + 1),
                                   __ATOMIC_RELAXED, __HIP_MEMORY_SCOPE_AGENT);
        }
    }
#undef PRE_AT
    // h_511 (== H[-2]) is in buf[1] (A-fragment layout); kernel end = device release.
}

// ---------------- y = h_final @ W2 + b2 (h in A-fragment layout) ----------------
__global__ __launch_bounds__(256) void out_gemm(const unsigned short* __restrict__ hfin,
                                                const float* __restrict__ W2,
                                                const float* __restrict__ b2,
                                                float* __restrict__ out) {
    int b = blockIdx.x;        // batch row, 64
    int j = threadIdx.x;       // out col, 256
    int g = b >> 4, m = b & 15;
    float acc = b2[j];
    for (int ks = 0; ks < 32; ++ks) {
#pragma unroll
        for (int lkq = 0; lkq < 4; ++lkq) {
            const unsigned short* ch =
                hfin + ((size_t)((((g * 32 + ks) << 6) + (lkq << 4) + m)) << 3);
            int k0 = ks * 32 + lkq * 8;
#pragma unroll
            for (int jj = 0; jj < 8; ++jj)
                acc = fmaf(bf2f(ch[jj]), W2[(size_t)(k0 + jj) * DOUT + j], acc);
        }
    }
    out[(size_t)b * DOUT + j] = acc;
}

extern "C" void kernel_launch(void* const* d_in, const int* in_sizes, int n_in,
                              void* d_out, int out_size, void* d_ws, size_t ws_size,
                              hipStream_t stream) {
    const float* x  = (const float*)d_in[0];
    const float* Wx = (const float*)d_in[1];
    const float* Wh = (const float*)d_in[2];
    const float* b  = (const float*)d_in[3];
    const float* W2 = (const float*)d_in[4];
    const float* b2 = (const float*)d_in[5];
    float* out = (float*)d_out;

    // workspace carve (~81 MB)
    char* ws = (char*)d_ws;
    unsigned*       flags = (unsigned*)ws;                                   // 4 KB
    unsigned short* hbuf  = (unsigned short*)(ws + 4096);                    // 256 KB
    unsigned short* xb    = (unsigned short*)(ws + 4096 + 2 * BATCH * HID * 2); // 16 MB
    unsigned short* wxtb  = xb + (size_t)T_STEPS * BATCH * DIN;              // 0.5 MB
    ull*            pre_r = (ull*)(wxtb + (size_t)HID * DIN);                // 64 MB

    (void)hipMemsetAsync(flags, 0, 4096, stream);
    convert_x<<<8192, 256, 0, stream>>>(x, xb);
    convert_wxt<<<1024, 256, 0, stream>>>(Wx, wxtb);
    gemm_pre<<<dim3(512, 16), 256, 0, stream>>>(xb, wxtb, b, pre_r);
    rnn_persistent<<<NBLK, 256, 0, stream>>>(Wh, pre_r, hbuf, flags);
    out_gemm<<<64, 256, 0, stream>>>(hbuf + (size_t)BATCH * HID, W2, b2, out);
}